// Round 12
// baseline (337.296 us; speedup 1.0000x reference)
//
#include <hip/hip_runtime.h>

#define BATCH 32
#define CIN   256
#define CHALF 128
#define NPIX  3136   // 56*56
#define MPOOL 784    // 28*28
#define MPAD  896    // 784 padded to multiple of 32

typedef __bf16 bf16;
typedef __bf16 bf16x2 __attribute__((ext_vector_type(2)));
typedef __bf16 bf16x4 __attribute__((ext_vector_type(4)));
typedef __bf16 bf16x8 __attribute__((ext_vector_type(8)));
typedef float  f32x4  __attribute__((ext_vector_type(4)));

// ---------------------------------------------------------------------------
// k_cast: W1,W2,W3 fp32 -> Wcat[512][256] bf16
// ---------------------------------------------------------------------------
__global__ __launch_bounds__(256) void k_cast(
    const float* __restrict__ W1, const float* __restrict__ W2,
    const float* __restrict__ W3, bf16* __restrict__ Wcat)
{
    int u = blockIdx.x * 256 + threadIdx.x;
    int o = u >> 6, k4 = (u & 63) * 4;
    const float* src = (o < 128) ? (W1 + o * 256)
                     : (o < 256) ? (W2 + (o - 128) * 256)
                                 : (W3 + (o - 256) * 256);
    float4 v = *(const float4*)(src + k4);
    bf16x4 w = { (bf16)v.x, (bf16)v.y, (bf16)v.z, (bf16)v.w };
    *(bf16x4*)(Wcat + o * 256 + k4) = w;
}

// ---------------------------------------------------------------------------
// k_conv (unchanged): MFMA 1x1 convs + fused 2x2 max+avg pool.
// ---------------------------------------------------------------------------
#define XS_STRIDE   528
#define SLAB_STRIDE 520

__global__ __launch_bounds__(512) void k_conv(
    const float* __restrict__ x, const bf16* __restrict__ Wcat,
    bf16* __restrict__ c2n, bf16* __restrict__ c1pT, bf16* __restrict__ c3p)
{
    const int h2 = blockIdx.x, b = blockIdx.y;
    const int t = threadIdx.x;
    const int lane = t & 63, wave = t >> 6;
    const int l15 = lane & 15, lg = lane >> 4;

    __shared__ __align__(16) unsigned char smem[59136];

    if (h2 == 0) {
        float4 z = {0.f, 0.f, 0.f, 0.f};
        float4* p1 = (float4*)(c1pT + (size_t)b * MPAD * CHALF + (size_t)MPOOL * CHALF);
        for (int u = t; u < 1792; u += 512) p1[u] = z;
        bf16* p3 = c3p + (size_t)b * CIN * MPAD + MPOOL;
        for (int u = t; u < 256 * 14; u += 512) {
            int c = u / 14, g = u % 14;
            *(float4*)((char*)(p3 + (size_t)c * MPAD) + g * 16) = z;
        }
    }

    {
        const float* xb = x + (size_t)b * CIN * NPIX + h2 * 112;
        float vv[14][4];
        #pragma unroll
        for (int i = 0; i < 14; ++i) {
            int u = t + i * 512;
            int c4 = u / 112, n = u - c4 * 112;
            const float* s = xb + (size_t)(c4 * 4) * NPIX + n;
            vv[i][0] = s[0];
            vv[i][1] = s[NPIX];
            vv[i][2] = s[2 * NPIX];
            vv[i][3] = s[3 * NPIX];
        }
        #pragma unroll
        for (int i = 0; i < 14; ++i) {
            int u = t + i * 512;
            int c4 = u / 112, n = u - c4 * 112;
            bf16x4 w = {(bf16)vv[i][0], (bf16)vv[i][1], (bf16)vv[i][2], (bf16)vv[i][3]};
            *(bf16x4*)(smem + n * XS_STRIDE + c4 * 8) = w;
        }
    }
    __syncthreads();

    f32x4 acc[4][7];
    #pragma unroll
    for (int fo = 0; fo < 4; ++fo)
        #pragma unroll
        for (int fn = 0; fn < 7; ++fn) {
            f32x4 zz = {0.f, 0.f, 0.f, 0.f};
            acc[fo][fn] = zz;
        }
    {
        const int o0 = wave * 64;
        const bf16* wbase = Wcat + (size_t)(o0 + l15) * 256 + lg * 8;
        const unsigned char* xsb = smem + l15 * XS_STRIDE + lg * 16;
        #pragma unroll
        for (int ks = 0; ks < 8; ++ks) {
            bf16x8 afr[4], bfr[7];
            #pragma unroll
            for (int fo = 0; fo < 4; ++fo)
                afr[fo] = *(const bf16x8*)(wbase + fo * 16 * 256 + ks * 32);
            #pragma unroll
            for (int fn = 0; fn < 7; ++fn)
                bfr[fn] = *(const bf16x8*)(xsb + fn * 16 * XS_STRIDE + ks * 64);
            #pragma unroll
            for (int fo = 0; fo < 4; ++fo)
                #pragma unroll
                for (int fn = 0; fn < 7; ++fn)
                    acc[fo][fn] = __builtin_amdgcn_mfma_f32_16x16x32_bf16(
                        afr[fo], bfr[fn], acc[fo][fn], 0, 0, 0);
        }
    }

    __syncthreads();
    if (wave < 4) {
        #pragma unroll
        for (int fo = 0; fo < 4; ++fo)
            #pragma unroll
            for (int fn = 0; fn < 7; ++fn) {
                int n = fn * 16 + l15;
                int ol = wave * 64 + fo * 16 + lg * 4;
                f32x4 a = acc[fo][fn];
                bf16x4 w = {(bf16)a[0], (bf16)a[1], (bf16)a[2], (bf16)a[3]};
                *(bf16x4*)(smem + n * SLAB_STRIDE + ol * 2) = w;
            }
    }
    __syncthreads();
    {
        bf16* dst = c1pT + (size_t)b * MPAD * CHALF + (size_t)h2 * 28 * CHALF;
        for (int u = t; u < 896; u += 512) {
            int w2 = u >> 5, o4 = (u & 31) * 4;
            bf16x4 r0 = *(bf16x4*)(smem + (2 * w2)      * SLAB_STRIDE + o4 * 2);
            bf16x4 r1 = *(bf16x4*)(smem + (2 * w2 + 1)  * SLAB_STRIDE + o4 * 2);
            bf16x4 r2 = *(bf16x4*)(smem + (56 + 2 * w2) * SLAB_STRIDE + o4 * 2);
            bf16x4 r3 = *(bf16x4*)(smem + (57 + 2 * w2) * SLAB_STRIDE + o4 * 2);
            bf16x4 o_;
            #pragma unroll
            for (int j = 0; j < 4; ++j) {
                float p0 = (float)r0[j], p1 = (float)r1[j];
                float p2 = (float)r2[j], p3 = (float)r3[j];
                float mx = fmaxf(fmaxf(p0, p1), fmaxf(p2, p3));
                float av = (p0 + p1 + p2 + p3) * 0.25f;
                o_[j] = (bf16)(mx + av);
            }
            *(bf16x4*)(dst + (size_t)w2 * CHALF + o4) = o_;
        }
    }
    {
        bf16* dst = c2n + (size_t)b * NPIX * CHALF + (size_t)h2 * 112 * CHALF;
        for (int u = t; u < 3584; u += 512) {
            int n = u >> 5, o4 = (u & 31) * 4;
            bf16x4 v = *(bf16x4*)(smem + n * SLAB_STRIDE + 256 + o4 * 2);
            *(bf16x4*)(dst + (size_t)n * CHALF + o4) = v;
        }
    }

    __syncthreads();
    if (wave >= 4) {
        #pragma unroll
        for (int fo = 0; fo < 4; ++fo)
            #pragma unroll
            for (int fn = 0; fn < 7; ++fn) {
                int n = fn * 16 + l15;
                int ol = (wave - 4) * 64 + fo * 16 + lg * 4;
                f32x4 a = acc[fo][fn];
                bf16x4 w = {(bf16)a[0], (bf16)a[1], (bf16)a[2], (bf16)a[3]};
                *(bf16x4*)(smem + n * SLAB_STRIDE + ol * 2) = w;
            }
    }
    __syncthreads();
    {
        bf16* dst = c3p + (size_t)b * CIN * MPAD + h2 * 28;
        for (int u = t; u < 3584; u += 512) {
            int c = u / 14, w2p = u - c * 14;
            bf16x2 o_;
            #pragma unroll
            for (int k = 0; k < 2; ++k) {
                int w2 = 2 * w2p + k;
                float p0 = (float)*(bf16*)(smem + (2 * w2)      * SLAB_STRIDE + c * 2);
                float p1 = (float)*(bf16*)(smem + (2 * w2 + 1)  * SLAB_STRIDE + c * 2);
                float p2 = (float)*(bf16*)(smem + (56 + 2 * w2) * SLAB_STRIDE + c * 2);
                float p3 = (float)*(bf16*)(smem + (57 + 2 * w2) * SLAB_STRIDE + c * 2);
                float mx = fmaxf(fmaxf(p0, p1), fmaxf(p2, p3));
                float av = (p0 + p1 + p2 + p3) * 0.25f;
                o_[k] = (bf16)(mx + av);
            }
            *(bf16x2*)(dst + (size_t)c * MPAD + 2 * w2p) = o_;
        }
    }
}

// ---------------------------------------------------------------------------
// k_attn v9 = v8 with the PV phase reading V DIRECTLY from global (L2-hot):
// drops the 16 KB V-stage round trip (1.3 MB LDS traffic) and all 28 PV
// barriers; P_lds is read-only in the loop. V-frags use an explicit 2-deep
// register pipeline (named v0/v1 sets, issue-before-use); chunks 0/1 are
// issued before the P-pack barrier so their latency hides under pack+barrier.
// S phase / softmax / P pack identical to v8 (proven).
// ---------------------------------------------------------------------------
#define STG_OFF 114688

__global__ __launch_bounds__(512) void k_attn(
    const bf16* __restrict__ c2n,
    const bf16* __restrict__ c1pT,
    const bf16* __restrict__ c3p,
    const float* __restrict__ x,
    const float* __restrict__ gamma,
    float* __restrict__ out)
{
    const int nb = blockIdx.x, b = blockIdx.y;
    const int n0 = nb * 64;
    const int t = threadIdx.x;
    const int lane = t & 63, wave = t >> 6;
    const int l15 = lane & 15, lg = lane >> 4;
    const int p = wave & 3, h = wave >> 2;

    __shared__ __align__(16) unsigned char smem[147456];
    unsigned char* stg = smem + STG_OFF;
    float* EX = (float*)stg;

    // ---- B-frags: c2 columns for n = n0 + p*16 + l15 (regs, loaded once) ---
    bf16x8 bq[4];
    {
        const bf16* c2b = c2n + ((size_t)b * NPIX + n0 + p * 16 + l15) * CHALF + lg * 8;
        #pragma unroll
        for (int k = 0; k < 4; ++k) bq[k] = *(const bf16x8*)(c2b + k * 32);
    }
    const bf16* c1b = c1pT + (size_t)b * MPAD * CHALF;
    const bf16* c3b = c3p + (size_t)b * CIN * MPAD;

    // ---- S staging addressing: chunk = [64 rows][16 slots x 16B] = 16 KB ---
    const int r0 = t >> 4, s0 = t & 15;
    const int cs = (s0 & 8) | ((s0 & 7) ^ (r0 & 7));
    const bf16* sA = c1b + (size_t)r0 * CHALF + cs * 8;
    const bf16* sB = c1b + (size_t)(448 + r0) * CHALF + cs * 8;

    uint4 rXa, rXb, rYa, rYb;
    rXa = *(const uint4*)(sA);
    rXb = *(const uint4*)(sB);
    *(uint4*)(stg + t * 16) = rXa;
    *(uint4*)(stg + 8192 + t * 16) = rXb;
    rYa = *(const uint4*)(sA + 4096);
    rYb = *(const uint4*)(sB + 4096);
    __syncthreads();

    f32x4 sacc[28];
    #pragma unroll
    for (int j = 0; j < 28; ++j) {
        f32x4 z = {0.f, 0.f, 0.f, 0.f};
        sacc[j] = z;
    }

    #pragma unroll
    for (int mc = 0; mc < 14; ++mc) {
        const unsigned char* bufc = stg + (mc & 1) * 16384;
        unsigned char* bufn = stg + ((mc & 1) ^ 1) * 16384;
        if (mc + 1 < 14) {
            if (mc & 1) { *(uint4*)(bufn + t * 16) = rXa; *(uint4*)(bufn + 8192 + t * 16) = rXb; }
            else        { *(uint4*)(bufn + t * 16) = rYa; *(uint4*)(bufn + 8192 + t * 16) = rYb; }
        }
        if (mc + 2 < 14) {
            if (mc & 1) { rYa = *(const uint4*)(sA + (mc + 2) * 4096); rYb = *(const uint4*)(sB + (mc + 2) * 4096); }
            else        { rXa = *(const uint4*)(sA + (mc + 2) * 4096); rXb = *(const uint4*)(sB + (mc + 2) * 4096); }
        }
        #pragma unroll
        for (int sf = 0; sf < 2; ++sf) {
            bf16x8 af[4];
            #pragma unroll
            for (int k = 0; k < 4; ++k)
                af[k] = *(const bf16x8*)(bufc + h * 8192 + (sf * 16 + l15) * 256
                                         + ((lg * 16 + k * 64) ^ ((l15 & 7) << 4)));
            #pragma unroll
            for (int k = 0; k < 4; ++k)
                sacc[mc * 2 + sf] = __builtin_amdgcn_mfma_f32_16x16x32_bf16(
                    af[k], bq[k], sacc[mc * 2 + sf], 0, 0, 0);
        }
        __syncthreads();
    }

    // ---- in-register softmax; lane n = p*16+l15 holds its 448-m half -------
    float mx = -1e30f;
    #pragma unroll
    for (int j = 0; j < 28; ++j) {
        if (h == 0 || j < 21)
            mx = fmaxf(mx, fmaxf(fmaxf(sacc[j][0], sacc[j][1]),
                                 fmaxf(sacc[j][2], sacc[j][3])));
    }
    mx = fmaxf(mx, __shfl_xor(mx, 16));
    mx = fmaxf(mx, __shfl_xor(mx, 32));
    if (lane < 16) EX[wave * 16 + l15] = mx;
    __syncthreads();
    mx = fmaxf(mx, EX[(wave ^ 4) * 16 + l15]);

    float s = 0.f;
    #pragma unroll
    for (int j = 0; j < 28; ++j) {
        if (h == 0 || j < 21) {
            #pragma unroll
            for (int r = 0; r < 4; ++r) {
                float e = __expf(sacc[j][r] - mx);
                sacc[j][r] = e;
                s += e;
            }
        }
    }
    s += __shfl_xor(s, 16);
    s += __shfl_xor(s, 32);
    if (lane < 16) EX[128 + wave * 16 + l15] = s;
    __syncthreads();
    s += EX[128 + (wave ^ 4) * 16 + l15];
    const float ri = 1.f / s;

    // ---- pre-issue PV chunks 0,1 V-frags (hide under pack + barrier) -------
    const int wn = h, wq = p;
    const bf16* c3w = c3b + (size_t)(wq * 64 + l15) * MPAD + lg * 8;
    bf16x8 v0[4], v1[4];
    #pragma unroll
    for (int fc = 0; fc < 4; ++fc) {
        v0[fc] = *(const bf16x8*)(c3w + (size_t)fc * 16 * MPAD);
        v1[fc] = *(const bf16x8*)(c3w + (size_t)fc * 16 * MPAD + 32);
    }

    // ---- pack normalized P bf16 -> P_lds (single swizzled b64 per frag) ----
    {
        const int n = p * 16 + l15;
        const unsigned sw = (unsigned)((n & 7) << 4);
        const unsigned rowb = (unsigned)(n * 1792);
        #pragma unroll
        for (int j = 0; j < 28; ++j) {
            bf16x4 w;
            if (h == 0 || j < 21) {
                w = bf16x4{ (bf16)(sacc[j][0] * ri), (bf16)(sacc[j][1] * ri),
                            (bf16)(sacc[j][2] * ri), (bf16)(sacc[j][3] * ri) };
            } else {
                w = bf16x4{ (bf16)0.f, (bf16)0.f, (bf16)0.f, (bf16)0.f };
            }
            unsigned byte = rowb + (unsigned)(h * 896 + j * 32 + lg * 8);
            *(bf16x4*)(smem + (byte ^ sw)) = w;
        }
    }
    __syncthreads();    // P complete; P_lds read-only from here

    // ---- PV: barrier-free loop, V direct from global (L2-hot), 2-deep ------
    f32x4 acc2[2][4];
    #pragma unroll
    for (int fn = 0; fn < 2; ++fn)
        #pragma unroll
        for (int fc = 0; fc < 4; ++fc) {
            f32x4 z = {0.f, 0.f, 0.f, 0.f};
            acc2[fn][fc] = z;
        }

    const int nA0 = wn * 32 + l15, nA1 = nA0 + 16;
    const unsigned swA0 = (unsigned)((nA0 & 7) << 4), swA1 = (unsigned)((nA1 & 7) << 4);
    const unsigned rbA0 = (unsigned)(nA0 * 1792), rbA1 = (unsigned)(nA1 * 1792);

    #pragma unroll
    for (int ks = 0; ks < 28; ks += 2) {
        // chunk ks with v0
        {
            unsigned mb = (unsigned)((ks * 32 + lg * 8) * 2);
            bf16x8 af0 = *(const bf16x8*)(smem + ((rbA0 + mb) ^ swA0));
            bf16x8 af1 = *(const bf16x8*)(smem + ((rbA1 + mb) ^ swA1));
            #pragma unroll
            for (int fc = 0; fc < 4; ++fc) {
                acc2[0][fc] = __builtin_amdgcn_mfma_f32_16x16x32_bf16(af0, v0[fc], acc2[0][fc], 0, 0, 0);
                acc2[1][fc] = __builtin_amdgcn_mfma_f32_16x16x32_bf16(af1, v0[fc], acc2[1][fc], 0, 0, 0);
            }
        }
        if (ks + 2 < 28) {
            #pragma unroll
            for (int fc = 0; fc < 4; ++fc)
                v0[fc] = *(const bf16x8*)(c3w + (size_t)fc * 16 * MPAD + (ks + 2) * 32);
        }
        // chunk ks+1 with v1
        {
            unsigned mb = (unsigned)(((ks + 1) * 32 + lg * 8) * 2);
            bf16x8 af0 = *(const bf16x8*)(smem + ((rbA0 + mb) ^ swA0));
            bf16x8 af1 = *(const bf16x8*)(smem + ((rbA1 + mb) ^ swA1));
            #pragma unroll
            for (int fc = 0; fc < 4; ++fc) {
                acc2[0][fc] = __builtin_amdgcn_mfma_f32_16x16x32_bf16(af0, v1[fc], acc2[0][fc], 0, 0, 0);
                acc2[1][fc] = __builtin_amdgcn_mfma_f32_16x16x32_bf16(af1, v1[fc], acc2[1][fc], 0, 0, 0);
            }
        }
        if (ks + 3 < 28) {
            #pragma unroll
            for (int fc = 0; fc < 4; ++fc)
                v1[fc] = *(const bf16x8*)(c3w + (size_t)fc * 16 * MPAD + (ks + 3) * 32);
        }
    }

    // ---- epilogue: transpose via LDS, out = g*refined + x ------------------
    __syncthreads();    // all P_lds reads done before overwrite
    float* R = (float*)smem;    // [64][257]
    #pragma unroll
    for (int fn = 0; fn < 2; ++fn)
        #pragma unroll
        for (int fc = 0; fc < 4; ++fc) {
            int c = wq * 64 + fc * 16 + l15;
            #pragma unroll
            for (int r = 0; r < 4; ++r) {
                int n = wn * 32 + fn * 16 + lg * 4 + r;
                R[n * 257 + c] = acc2[fn][fc][r];
            }
        }
    __syncthreads();
    const float g = gamma[0];
    const float* xb = x + (size_t)b * CIN * NPIX + n0;
    float* ob = out + (size_t)b * CIN * NPIX + n0;
    #pragma unroll 4
    for (int i = 0; i < 32; ++i) {
        int idx = t + i * 512;                  // 256 c x 64 n
        int c = idx >> 6, nn = idx & 63;
        size_t off = (size_t)c * NPIX + nn;
        ob[off] = g * R[nn * 257 + c] + xb[off];
    }
}

extern "C" void kernel_launch(void* const* d_in, const int* in_sizes, int n_in,
                              void* d_out, int out_size, void* d_ws, size_t ws_size,
                              hipStream_t stream) {
    const float* x     = (const float*)d_in[0];
    const float* W1    = (const float*)d_in[1];
    const float* W2    = (const float*)d_in[2];
    const float* W3    = (const float*)d_in[3];
    const float* gamma = (const float*)d_in[4];
    float* out = (float*)d_out;

    bf16* ws   = (bf16*)d_ws;
    bf16* Wcat = ws;                                       // 512*256
    bf16* c2n  = Wcat + (size_t)512 * 256;                 // 32*3136*128
    bf16* c1pT = c2n + (size_t)BATCH * NPIX * CHALF;       // 32*896*128
    bf16* c3p  = c1pT + (size_t)BATCH * MPAD * CHALF;      // 32*256*896

    k_cast<<<128, 256, 0, stream>>>(W1, W2, W3, Wcat);
    k_conv<<<dim3(28, BATCH), 512, 0, stream>>>(x, Wcat, c2n, c1pT, c3p);
    k_attn<<<dim3(49, BATCH), 512, 0, stream>>>(c2n, c1pT, c3p, x, gamma, out);
}

// Round 13
// 308.880 us; speedup vs baseline: 1.0920x; 1.0920x over previous
//
#include <hip/hip_runtime.h>

#define BATCH 32
#define CIN   256
#define CHALF 128
#define NPIX  3136   // 56*56
#define MPOOL 784    // 28*28
#define MPAD  896    // 784 padded to multiple of 32

typedef __bf16 bf16;
typedef __bf16 bf16x2 __attribute__((ext_vector_type(2)));
typedef __bf16 bf16x4 __attribute__((ext_vector_type(4)));
typedef __bf16 bf16x8 __attribute__((ext_vector_type(8)));
typedef float  f32x4  __attribute__((ext_vector_type(4)));

// ---------------------------------------------------------------------------
// k_cast: W1,W2,W3 fp32 -> Wcat[512][256] bf16
// ---------------------------------------------------------------------------
__global__ __launch_bounds__(256) void k_cast(
    const float* __restrict__ W1, const float* __restrict__ W2,
    const float* __restrict__ W3, bf16* __restrict__ Wcat)
{
    int u = blockIdx.x * 256 + threadIdx.x;
    int o = u >> 6, k4 = (u & 63) * 4;
    const float* src = (o < 128) ? (W1 + o * 256)
                     : (o < 256) ? (W2 + (o - 128) * 256)
                                 : (W3 + (o - 256) * 256);
    float4 v = *(const float4*)(src + k4);
    bf16x4 w = { (bf16)v.x, (bf16)v.y, (bf16)v.z, (bf16)v.w };
    *(bf16x4*)(Wcat + o * 256 + k4) = w;
}

// ---------------------------------------------------------------------------
// k_conv (unchanged): MFMA 1x1 convs + fused 2x2 max+avg pool.
// ---------------------------------------------------------------------------
#define XS_STRIDE   528
#define SLAB_STRIDE 520

__global__ __launch_bounds__(512) void k_conv(
    const float* __restrict__ x, const bf16* __restrict__ Wcat,
    bf16* __restrict__ c2n, bf16* __restrict__ c1pT, bf16* __restrict__ c3p)
{
    const int h2 = blockIdx.x, b = blockIdx.y;
    const int t = threadIdx.x;
    const int lane = t & 63, wave = t >> 6;
    const int l15 = lane & 15, lg = lane >> 4;

    __shared__ __align__(16) unsigned char smem[59136];

    if (h2 == 0) {
        float4 z = {0.f, 0.f, 0.f, 0.f};
        float4* p1 = (float4*)(c1pT + (size_t)b * MPAD * CHALF + (size_t)MPOOL * CHALF);
        for (int u = t; u < 1792; u += 512) p1[u] = z;
        bf16* p3 = c3p + (size_t)b * CIN * MPAD + MPOOL;
        for (int u = t; u < 256 * 14; u += 512) {
            int c = u / 14, g = u % 14;
            *(float4*)((char*)(p3 + (size_t)c * MPAD) + g * 16) = z;
        }
    }

    {
        const float* xb = x + (size_t)b * CIN * NPIX + h2 * 112;
        float vv[14][4];
        #pragma unroll
        for (int i = 0; i < 14; ++i) {
            int u = t + i * 512;
            int c4 = u / 112, n = u - c4 * 112;
            const float* s = xb + (size_t)(c4 * 4) * NPIX + n;
            vv[i][0] = s[0];
            vv[i][1] = s[NPIX];
            vv[i][2] = s[2 * NPIX];
            vv[i][3] = s[3 * NPIX];
        }
        #pragma unroll
        for (int i = 0; i < 14; ++i) {
            int u = t + i * 512;
            int c4 = u / 112, n = u - c4 * 112;
            bf16x4 w = {(bf16)vv[i][0], (bf16)vv[i][1], (bf16)vv[i][2], (bf16)vv[i][3]};
            *(bf16x4*)(smem + n * XS_STRIDE + c4 * 8) = w;
        }
    }
    __syncthreads();

    f32x4 acc[4][7];
    #pragma unroll
    for (int fo = 0; fo < 4; ++fo)
        #pragma unroll
        for (int fn = 0; fn < 7; ++fn) {
            f32x4 zz = {0.f, 0.f, 0.f, 0.f};
            acc[fo][fn] = zz;
        }
    {
        const int o0 = wave * 64;
        const bf16* wbase = Wcat + (size_t)(o0 + l15) * 256 + lg * 8;
        const unsigned char* xsb = smem + l15 * XS_STRIDE + lg * 16;
        #pragma unroll
        for (int ks = 0; ks < 8; ++ks) {
            bf16x8 afr[4], bfr[7];
            #pragma unroll
            for (int fo = 0; fo < 4; ++fo)
                afr[fo] = *(const bf16x8*)(wbase + fo * 16 * 256 + ks * 32);
            #pragma unroll
            for (int fn = 0; fn < 7; ++fn)
                bfr[fn] = *(const bf16x8*)(xsb + fn * 16 * XS_STRIDE + ks * 64);
            #pragma unroll
            for (int fo = 0; fo < 4; ++fo)
                #pragma unroll
                for (int fn = 0; fn < 7; ++fn)
                    acc[fo][fn] = __builtin_amdgcn_mfma_f32_16x16x32_bf16(
                        afr[fo], bfr[fn], acc[fo][fn], 0, 0, 0);
        }
    }

    __syncthreads();
    if (wave < 4) {
        #pragma unroll
        for (int fo = 0; fo < 4; ++fo)
            #pragma unroll
            for (int fn = 0; fn < 7; ++fn) {
                int n = fn * 16 + l15;
                int ol = wave * 64 + fo * 16 + lg * 4;
                f32x4 a = acc[fo][fn];
                bf16x4 w = {(bf16)a[0], (bf16)a[1], (bf16)a[2], (bf16)a[3]};
                *(bf16x4*)(smem + n * SLAB_STRIDE + ol * 2) = w;
            }
    }
    __syncthreads();
    {
        bf16* dst = c1pT + (size_t)b * MPAD * CHALF + (size_t)h2 * 28 * CHALF;
        for (int u = t; u < 896; u += 512) {
            int w2 = u >> 5, o4 = (u & 31) * 4;
            bf16x4 r0 = *(bf16x4*)(smem + (2 * w2)      * SLAB_STRIDE + o4 * 2);
            bf16x4 r1 = *(bf16x4*)(smem + (2 * w2 + 1)  * SLAB_STRIDE + o4 * 2);
            bf16x4 r2 = *(bf16x4*)(smem + (56 + 2 * w2) * SLAB_STRIDE + o4 * 2);
            bf16x4 r3 = *(bf16x4*)(smem + (57 + 2 * w2) * SLAB_STRIDE + o4 * 2);
            bf16x4 o_;
            #pragma unroll
            for (int j = 0; j < 4; ++j) {
                float p0 = (float)r0[j], p1 = (float)r1[j];
                float p2 = (float)r2[j], p3 = (float)r3[j];
                float mx = fmaxf(fmaxf(p0, p1), fmaxf(p2, p3));
                float av = (p0 + p1 + p2 + p3) * 0.25f;
                o_[j] = (bf16)(mx + av);
            }
            *(bf16x4*)(dst + (size_t)w2 * CHALF + o4) = o_;
        }
    }
    {
        bf16* dst = c2n + (size_t)b * NPIX * CHALF + (size_t)h2 * 112 * CHALF;
        for (int u = t; u < 3584; u += 512) {
            int n = u >> 5, o4 = (u & 31) * 4;
            bf16x4 v = *(bf16x4*)(smem + n * SLAB_STRIDE + 256 + o4 * 2);
            *(bf16x4*)(dst + (size_t)n * CHALF + o4) = v;
        }
    }

    __syncthreads();
    if (wave >= 4) {
        #pragma unroll
        for (int fo = 0; fo < 4; ++fo)
            #pragma unroll
            for (int fn = 0; fn < 7; ++fn) {
                int n = fn * 16 + l15;
                int ol = (wave - 4) * 64 + fo * 16 + lg * 4;
                f32x4 a = acc[fo][fn];
                bf16x4 w = {(bf16)a[0], (bf16)a[1], (bf16)a[2], (bf16)a[3]};
                *(bf16x4*)(smem + n * SLAB_STRIDE + ol * 2) = w;
            }
    }
    __syncthreads();
    {
        bf16* dst = c3p + (size_t)b * CIN * MPAD + h2 * 28;
        for (int u = t; u < 3584; u += 512) {
            int c = u / 14, w2p = u - c * 14;
            bf16x2 o_;
            #pragma unroll
            for (int k = 0; k < 2; ++k) {
                int w2 = 2 * w2p + k;
                float p0 = (float)*(bf16*)(smem + (2 * w2)      * SLAB_STRIDE + c * 2);
                float p1 = (float)*(bf16*)(smem + (2 * w2 + 1)  * SLAB_STRIDE + c * 2);
                float p2 = (float)*(bf16*)(smem + (56 + 2 * w2) * SLAB_STRIDE + c * 2);
                float p3 = (float)*(bf16*)(smem + (57 + 2 * w2) * SLAB_STRIDE + c * 2);
                float mx = fmaxf(fmaxf(p0, p1), fmaxf(p2, p3));
                float av = (p0 + p1 + p2 + p3) * 0.25f;
                o_[k] = (bf16)(mx + av);
            }
            *(bf16x2*)(dst + (size_t)c * MPAD + 2 * w2p) = o_;
        }
    }
}

// ---------------------------------------------------------------------------
// k_attn v10 = v8 with (a) S-phase wave decomposition ms=wave&3 (interleaved
// m-frag quarter) x ng=wave>>2 (32-n half): each A-frag read feeds 2 MFMAs,
// S-LDS reads 896->448 KB; (b) S staged in 2x32KB buffers carved from the
// (idle during S) P region: 128-m chunks, 7 barriers instead of 14.
// Softmax = in-register + 4-wave EX combine. P-pack / PV / epilogue = v8.
// ---------------------------------------------------------------------------
#define STG_OFF 114688

__global__ __launch_bounds__(512) void k_attn(
    const bf16* __restrict__ c2n,
    const bf16* __restrict__ c1pT,
    const bf16* __restrict__ c3p,
    const float* __restrict__ x,
    const float* __restrict__ gamma,
    float* __restrict__ out)
{
    const int nb = blockIdx.x, b = blockIdx.y;
    const int n0 = nb * 64;
    const int t = threadIdx.x;
    const int lane = t & 63, wave = t >> 6;
    const int l15 = lane & 15, lg = lane >> 4;
    const int ms = wave & 3, ng = wave >> 2;

    __shared__ __align__(16) unsigned char smem[147456];
    unsigned char* stg = smem + STG_OFF;          // PV stage region (32 KB)
    float* EX = (float*)stg;                      // softmax exchange (dead by PV)

    // ---- B-frags: c2 cols for n = n0 + ng*32 + nf*16 + l15 (regs) ----------
    bf16x8 bq[2][4];
    #pragma unroll
    for (int nf = 0; nf < 2; ++nf) {
        const bf16* c2b = c2n + ((size_t)b * NPIX + n0 + ng * 32 + nf * 16 + l15) * CHALF + lg * 8;
        #pragma unroll
        for (int k = 0; k < 4; ++k) bq[nf][k] = *(const bf16x8*)(c2b + k * 32);
    }
    const bf16* c1b = c1pT + (size_t)b * MPAD * CHALF;
    const bf16* c3b = c3p + (size_t)b * CIN * MPAD;

    // ---- S stage: 7 chunks of [128 m][128 c] = 32 KB, dbuf in P region -----
    // thread stages 4 rows-slots: u = t + i*512 -> row u>>4, slot u&15
    const int r0 = t >> 4, s0 = t & 15;
    const int cs = (s0 & 8) | ((s0 & 7) ^ (r0 & 7));    // involution slot swz
    const bf16* sS = c1b + (size_t)r0 * CHALF + cs * 8;

    uint4 rX[4], rY[4];
    #pragma unroll
    for (int i = 0; i < 4; ++i) rX[i] = *(const uint4*)(sS + (size_t)(i * 32) * CHALF);
    #pragma unroll
    for (int i = 0; i < 4; ++i) *(uint4*)(smem + (t + i * 512) * 16) = rX[i];
    #pragma unroll
    for (int i = 0; i < 4; ++i) rY[i] = *(const uint4*)(sS + (size_t)(128 + i * 32) * CHALF);
    __syncthreads();

    f32x4 sacc[7][2][2];    // [chunk][mi][nf]
    #pragma unroll
    for (int c = 0; c < 7; ++c)
        #pragma unroll
        for (int mi = 0; mi < 2; ++mi)
            #pragma unroll
            for (int nf = 0; nf < 2; ++nf) {
                f32x4 z = {0.f, 0.f, 0.f, 0.f};
                sacc[c][mi][nf] = z;
            }

    #pragma unroll
    for (int c = 0; c < 7; ++c) {
        const unsigned char* bufc = smem + (c & 1) * 32768;
        unsigned char* bufn = smem + ((c & 1) ^ 1) * 32768;
        if (c + 1 < 7) {
            if (c & 1) {
                #pragma unroll
                for (int i = 0; i < 4; ++i) *(uint4*)(bufn + (t + i * 512) * 16) = rX[i];
            } else {
                #pragma unroll
                for (int i = 0; i < 4; ++i) *(uint4*)(bufn + (t + i * 512) * 16) = rY[i];
            }
        }
        if (c + 2 < 7) {
            if (c & 1) {
                #pragma unroll
                for (int i = 0; i < 4; ++i) rY[i] = *(const uint4*)(sS + (size_t)((c + 2) * 128 + i * 32) * CHALF);
            } else {
                #pragma unroll
                for (int i = 0; i < 4; ++i) rX[i] = *(const uint4*)(sS + (size_t)((c + 2) * 128 + i * 32) * CHALF);
            }
        }
        // consume: wave reads m-frags mfl = ms, ms+4 of this chunk
        #pragma unroll
        for (int mi = 0; mi < 2; ++mi) {
            int mfl = ms + mi * 4;
            bf16x8 af[4];
            #pragma unroll
            for (int k = 0; k < 4; ++k)
                af[k] = *(const bf16x8*)(bufc + (mfl * 16 + l15) * 256
                                         + ((lg * 16 + k * 64) ^ ((l15 & 7) << 4)));
            #pragma unroll
            for (int k = 0; k < 4; ++k) {
                sacc[c][mi][0] = __builtin_amdgcn_mfma_f32_16x16x32_bf16(af[k], bq[0][k], sacc[c][mi][0], 0, 0, 0);
                sacc[c][mi][1] = __builtin_amdgcn_mfma_f32_16x16x32_bf16(af[k], bq[1][k], sacc[c][mi][1], 0, 0, 0);
            }
        }
        __syncthreads();
    }

    // ---- in-register softmax; lane holds 56 m per nf (frag gm = c*8+ms+4mi)
    float mx[2] = { -1e30f, -1e30f };
    #pragma unroll
    for (int c = 0; c < 7; ++c)
        #pragma unroll
        for (int mi = 0; mi < 2; ++mi) {
            if (c * 8 + 4 * mi + ms < 49) {     // frag fully valid (m < 784)
                #pragma unroll
                for (int nf = 0; nf < 2; ++nf) {
                    f32x4 v = sacc[c][mi][nf];
                    mx[nf] = fmaxf(mx[nf], fmaxf(fmaxf(v[0], v[1]), fmaxf(v[2], v[3])));
                }
            }
        }
    #pragma unroll
    for (int nf = 0; nf < 2; ++nf) {
        mx[nf] = fmaxf(mx[nf], __shfl_xor(mx[nf], 16));
        mx[nf] = fmaxf(mx[nf], __shfl_xor(mx[nf], 32));
    }
    if (lane < 16) {
        EX[(wave * 2 + 0) * 16 + l15] = mx[0];
        EX[(wave * 2 + 1) * 16 + l15] = mx[1];
    }
    __syncthreads();
    #pragma unroll
    for (int nf = 0; nf < 2; ++nf) {
        float m0 = EX[((ng * 4 + 0) * 2 + nf) * 16 + l15];
        float m1 = EX[((ng * 4 + 1) * 2 + nf) * 16 + l15];
        float m2 = EX[((ng * 4 + 2) * 2 + nf) * 16 + l15];
        float m3 = EX[((ng * 4 + 3) * 2 + nf) * 16 + l15];
        mx[nf] = fmaxf(fmaxf(m0, m1), fmaxf(m2, m3));
    }

    float sm[2] = { 0.f, 0.f };
    #pragma unroll
    for (int c = 0; c < 7; ++c)
        #pragma unroll
        for (int mi = 0; mi < 2; ++mi) {
            if (c * 8 + 4 * mi + ms < 49) {
                #pragma unroll
                for (int nf = 0; nf < 2; ++nf) {
                    #pragma unroll
                    for (int r = 0; r < 4; ++r) {
                        float e = __expf(sacc[c][mi][nf][r] - mx[nf]);
                        sacc[c][mi][nf][r] = e;
                        sm[nf] += e;
                    }
                }
            }
        }
    #pragma unroll
    for (int nf = 0; nf < 2; ++nf) {
        sm[nf] += __shfl_xor(sm[nf], 16);
        sm[nf] += __shfl_xor(sm[nf], 32);
    }
    if (lane < 16) {
        EX[256 + (wave * 2 + 0) * 16 + l15] = sm[0];
        EX[256 + (wave * 2 + 1) * 16 + l15] = sm[1];
    }
    __syncthreads();
    float ri[2];
    #pragma unroll
    for (int nf = 0; nf < 2; ++nf) {
        float s0v = EX[256 + ((ng * 4 + 0) * 2 + nf) * 16 + l15];
        float s1v = EX[256 + ((ng * 4 + 1) * 2 + nf) * 16 + l15];
        float s2v = EX[256 + ((ng * 4 + 2) * 2 + nf) * 16 + l15];
        float s3v = EX[256 + ((ng * 4 + 3) * 2 + nf) * 16 + l15];
        ri[nf] = 1.f / ((s0v + s1v) + (s2v + s3v));
    }

    // ---- pre-issue PV V-stage chunk 0 (regs; hides under pack+barrier) -----
    const int pc = t >> 2, ps = t & 3;
    const bf16* sV  = c3b + (size_t)pc * MPAD + ((ps ^ (pc & 3)) * 8);
    const bf16* sV2 = c3b + (size_t)(pc + 128) * MPAD + ((ps ^ (pc & 3)) * 8);
    uint4 rXa = *(const uint4*)(sV);
    uint4 rXb = *(const uint4*)(sV2);

    // ---- pack normalized P bf16 -> P_lds (single swizzled b64 per frag) ----
    {
        #pragma unroll
        for (int c = 0; c < 7; ++c)
            #pragma unroll
            for (int mi = 0; mi < 2; ++mi) {
                int gm = c * 8 + 4 * mi + ms;            // m-frag 0..55
                bool valid = gm < 49;
                #pragma unroll
                for (int nf = 0; nf < 2; ++nf) {
                    int n = ng * 32 + nf * 16 + l15;
                    bf16x4 w;
                    if (valid) {
                        w = bf16x4{ (bf16)(sacc[c][mi][nf][0] * ri[nf]),
                                    (bf16)(sacc[c][mi][nf][1] * ri[nf]),
                                    (bf16)(sacc[c][mi][nf][2] * ri[nf]),
                                    (bf16)(sacc[c][mi][nf][3] * ri[nf]) };
                    } else {
                        w = bf16x4{ (bf16)0.f, (bf16)0.f, (bf16)0.f, (bf16)0.f };
                    }
                    unsigned byte = (unsigned)(n * 1792 + gm * 32 + lg * 8)
                                  ^ (unsigned)((n & 7) << 4);
                    *(bf16x4*)(smem + byte) = w;
                }
            }
    }
    __syncthreads();    // P complete; EX dead -> stage region free for PV

    // ---- PV phase: identical to v8 -----------------------------------------
    *(uint4*)(stg + t * 16) = rXa;
    *(uint4*)(stg + 8192 + t * 16) = rXb;
    uint4 rYa = *(const uint4*)(sV + 32);
    uint4 rYb = *(const uint4*)(sV2 + 32);
    __syncthreads();

    const int wn = ng, wq = ms;
    f32x4 acc2[2][4];
    #pragma unroll
    for (int fn = 0; fn < 2; ++fn)
        #pragma unroll
        for (int fc = 0; fc < 4; ++fc) {
            f32x4 z = {0.f, 0.f, 0.f, 0.f};
            acc2[fn][fc] = z;
        }

    #pragma unroll
    for (int ks = 0; ks < 28; ++ks) {
        const unsigned char* bufc = stg + (ks & 1) * 16384;
        unsigned char* bufn = stg + ((ks & 1) ^ 1) * 16384;
        if (ks + 1 < 28) {
            if (ks & 1) { *(uint4*)(bufn + t * 16) = rXa; *(uint4*)(bufn + 8192 + t * 16) = rXb; }
            else        { *(uint4*)(bufn + t * 16) = rYa; *(uint4*)(bufn + 8192 + t * 16) = rYb; }
        }
        if (ks + 2 < 28) {
            if (ks & 1) { rYa = *(const uint4*)(sV + (ks + 2) * 32); rYb = *(const uint4*)(sV2 + (ks + 2) * 32); }
            else        { rXa = *(const uint4*)(sV + (ks + 2) * 32); rXb = *(const uint4*)(sV2 + (ks + 2) * 32); }
        }
        {
            int nA0 = wn * 32 + l15, nA1 = nA0 + 16;
            int mb = (ks * 32 + lg * 8) * 2;
            bf16x8 af0 = *(const bf16x8*)(smem + ((nA0 * 1792 + mb) ^ ((nA0 & 7) << 4)));
            bf16x8 af1 = *(const bf16x8*)(smem + ((nA1 * 1792 + mb) ^ ((nA1 & 7) << 4)));
            #pragma unroll
            for (int fc = 0; fc < 4; ++fc) {
                int c = wq * 64 + fc * 16 + l15;
                bf16x8 bfr = *(const bf16x8*)(bufc + c * 64 + ((lg ^ (c & 3)) * 16));
                acc2[0][fc] = __builtin_amdgcn_mfma_f32_16x16x32_bf16(af0, bfr, acc2[0][fc], 0, 0, 0);
                acc2[1][fc] = __builtin_amdgcn_mfma_f32_16x16x32_bf16(af1, bfr, acc2[1][fc], 0, 0, 0);
            }
        }
        __syncthreads();
    }

    // ---- epilogue: transpose via LDS, out = g*refined + x ------------------
    float* R = (float*)smem;    // [64][257], P_lds dead
    #pragma unroll
    for (int fn = 0; fn < 2; ++fn)
        #pragma unroll
        for (int fc = 0; fc < 4; ++fc) {
            int c = wq * 64 + fc * 16 + l15;
            #pragma unroll
            for (int r = 0; r < 4; ++r) {
                int n = wn * 32 + fn * 16 + lg * 4 + r;
                R[n * 257 + c] = acc2[fn][fc][r];
            }
        }
    __syncthreads();
    const float g = gamma[0];
    const float* xb = x + (size_t)b * CIN * NPIX + n0;
    float* ob = out + (size_t)b * CIN * NPIX + n0;
    #pragma unroll 4
    for (int i = 0; i < 32; ++i) {
        int idx = t + i * 512;                  // 256 c x 64 n
        int c = idx >> 6, nn = idx & 63;
        size_t off = (size_t)c * NPIX + nn;
        ob[off] = g * R[nn * 257 + c] + xb[off];
    }
}

extern "C" void kernel_launch(void* const* d_in, const int* in_sizes, int n_in,
                              void* d_out, int out_size, void* d_ws, size_t ws_size,
                              hipStream_t stream) {
    const float* x     = (const float*)d_in[0];
    const float* W1    = (const float*)d_in[1];
    const float* W2    = (const float*)d_in[2];
    const float* W3    = (const float*)d_in[3];
    const float* gamma = (const float*)d_in[4];
    float* out = (float*)d_out;

    bf16* ws   = (bf16*)d_ws;
    bf16* Wcat = ws;                                       // 512*256
    bf16* c2n  = Wcat + (size_t)512 * 256;                 // 32*3136*128
    bf16* c1pT = c2n + (size_t)BATCH * NPIX * CHALF;       // 32*896*128
    bf16* c3p  = c1pT + (size_t)BATCH * MPAD * CHALF;      // 32*256*896

    k_cast<<<128, 256, 0, stream>>>(W1, W2, W3, Wcat);
    k_conv<<<dim3(28, BATCH), 512, 0, stream>>>(x, Wcat, c2n, c1pT, c3p);
    k_attn<<<dim3(49, BATCH), 512, 0, stream>>>(c2n, c1pT, c3p, x, gamma, out);
}

// Round 14
// 243.168 us; speedup vs baseline: 1.3871x; 1.2702x over previous
//
#include <hip/hip_runtime.h>

#define BATCH 32
#define CIN   256
#define CHALF 128
#define NPIX  3136   // 56*56
#define MPOOL 784    // 28*28
#define MPAD  896    // 784 padded to multiple of 32

typedef __bf16 bf16;
typedef __bf16 bf16x2 __attribute__((ext_vector_type(2)));
typedef __bf16 bf16x4 __attribute__((ext_vector_type(4)));
typedef __bf16 bf16x8 __attribute__((ext_vector_type(8)));
typedef float  f32x4  __attribute__((ext_vector_type(4)));

// ---------------------------------------------------------------------------
// k_cast: W1,W2,W3 fp32 -> Wcat[512][256] bf16
// ---------------------------------------------------------------------------
__global__ __launch_bounds__(256) void k_cast(
    const float* __restrict__ W1, const float* __restrict__ W2,
    const float* __restrict__ W3, bf16* __restrict__ Wcat)
{
    int u = blockIdx.x * 256 + threadIdx.x;
    int o = u >> 6, k4 = (u & 63) * 4;
    const float* src = (o < 128) ? (W1 + o * 256)
                     : (o < 256) ? (W2 + (o - 128) * 256)
                                 : (W3 + (o - 256) * 256);
    float4 v = *(const float4*)(src + k4);
    bf16x4 w = { (bf16)v.x, (bf16)v.y, (bf16)v.z, (bf16)v.w };
    *(bf16x4*)(Wcat + o * 256 + k4) = w;
}

// ---------------------------------------------------------------------------
// k_conv (unchanged): MFMA 1x1 convs + fused 2x2 max+avg pool.
// ---------------------------------------------------------------------------
#define XS_STRIDE   528
#define SLAB_STRIDE 520

__global__ __launch_bounds__(512) void k_conv(
    const float* __restrict__ x, const bf16* __restrict__ Wcat,
    bf16* __restrict__ c2n, bf16* __restrict__ c1pT, bf16* __restrict__ c3p)
{
    const int h2 = blockIdx.x, b = blockIdx.y;
    const int t = threadIdx.x;
    const int lane = t & 63, wave = t >> 6;
    const int l15 = lane & 15, lg = lane >> 4;

    __shared__ __align__(16) unsigned char smem[59136];

    if (h2 == 0) {
        float4 z = {0.f, 0.f, 0.f, 0.f};
        float4* p1 = (float4*)(c1pT + (size_t)b * MPAD * CHALF + (size_t)MPOOL * CHALF);
        for (int u = t; u < 1792; u += 512) p1[u] = z;
        bf16* p3 = c3p + (size_t)b * CIN * MPAD + MPOOL;
        for (int u = t; u < 256 * 14; u += 512) {
            int c = u / 14, g = u % 14;
            *(float4*)((char*)(p3 + (size_t)c * MPAD) + g * 16) = z;
        }
    }

    {
        const float* xb = x + (size_t)b * CIN * NPIX + h2 * 112;
        float vv[14][4];
        #pragma unroll
        for (int i = 0; i < 14; ++i) {
            int u = t + i * 512;
            int c4 = u / 112, n = u - c4 * 112;
            const float* s = xb + (size_t)(c4 * 4) * NPIX + n;
            vv[i][0] = s[0];
            vv[i][1] = s[NPIX];
            vv[i][2] = s[2 * NPIX];
            vv[i][3] = s[3 * NPIX];
        }
        #pragma unroll
        for (int i = 0; i < 14; ++i) {
            int u = t + i * 512;
            int c4 = u / 112, n = u - c4 * 112;
            bf16x4 w = {(bf16)vv[i][0], (bf16)vv[i][1], (bf16)vv[i][2], (bf16)vv[i][3]};
            *(bf16x4*)(smem + n * XS_STRIDE + c4 * 8) = w;
        }
    }
    __syncthreads();

    f32x4 acc[4][7];
    #pragma unroll
    for (int fo = 0; fo < 4; ++fo)
        #pragma unroll
        for (int fn = 0; fn < 7; ++fn) {
            f32x4 zz = {0.f, 0.f, 0.f, 0.f};
            acc[fo][fn] = zz;
        }
    {
        const int o0 = wave * 64;
        const bf16* wbase = Wcat + (size_t)(o0 + l15) * 256 + lg * 8;
        const unsigned char* xsb = smem + l15 * XS_STRIDE + lg * 16;
        #pragma unroll
        for (int ks = 0; ks < 8; ++ks) {
            bf16x8 afr[4], bfr[7];
            #pragma unroll
            for (int fo = 0; fo < 4; ++fo)
                afr[fo] = *(const bf16x8*)(wbase + fo * 16 * 256 + ks * 32);
            #pragma unroll
            for (int fn = 0; fn < 7; ++fn)
                bfr[fn] = *(const bf16x8*)(xsb + fn * 16 * XS_STRIDE + ks * 64);
            #pragma unroll
            for (int fo = 0; fo < 4; ++fo)
                #pragma unroll
                for (int fn = 0; fn < 7; ++fn)
                    acc[fo][fn] = __builtin_amdgcn_mfma_f32_16x16x32_bf16(
                        afr[fo], bfr[fn], acc[fo][fn], 0, 0, 0);
        }
    }

    __syncthreads();
    if (wave < 4) {
        #pragma unroll
        for (int fo = 0; fo < 4; ++fo)
            #pragma unroll
            for (int fn = 0; fn < 7; ++fn) {
                int n = fn * 16 + l15;
                int ol = wave * 64 + fo * 16 + lg * 4;
                f32x4 a = acc[fo][fn];
                bf16x4 w = {(bf16)a[0], (bf16)a[1], (bf16)a[2], (bf16)a[3]};
                *(bf16x4*)(smem + n * SLAB_STRIDE + ol * 2) = w;
            }
    }
    __syncthreads();
    {
        bf16* dst = c1pT + (size_t)b * MPAD * CHALF + (size_t)h2 * 28 * CHALF;
        for (int u = t; u < 896; u += 512) {
            int w2 = u >> 5, o4 = (u & 31) * 4;
            bf16x4 r0 = *(bf16x4*)(smem + (2 * w2)      * SLAB_STRIDE + o4 * 2);
            bf16x4 r1 = *(bf16x4*)(smem + (2 * w2 + 1)  * SLAB_STRIDE + o4 * 2);
            bf16x4 r2 = *(bf16x4*)(smem + (56 + 2 * w2) * SLAB_STRIDE + o4 * 2);
            bf16x4 r3 = *(bf16x4*)(smem + (57 + 2 * w2) * SLAB_STRIDE + o4 * 2);
            bf16x4 o_;
            #pragma unroll
            for (int j = 0; j < 4; ++j) {
                float p0 = (float)r0[j], p1 = (float)r1[j];
                float p2 = (float)r2[j], p3 = (float)r3[j];
                float mx = fmaxf(fmaxf(p0, p1), fmaxf(p2, p3));
                float av = (p0 + p1 + p2 + p3) * 0.25f;
                o_[j] = (bf16)(mx + av);
            }
            *(bf16x4*)(dst + (size_t)w2 * CHALF + o4) = o_;
        }
    }
    {
        bf16* dst = c2n + (size_t)b * NPIX * CHALF + (size_t)h2 * 112 * CHALF;
        for (int u = t; u < 3584; u += 512) {
            int n = u >> 5, o4 = (u & 31) * 4;
            bf16x4 v = *(bf16x4*)(smem + n * SLAB_STRIDE + 256 + o4 * 2);
            *(bf16x4*)(dst + (size_t)n * CHALF + o4) = v;
        }
    }

    __syncthreads();
    if (wave >= 4) {
        #pragma unroll
        for (int fo = 0; fo < 4; ++fo)
            #pragma unroll
            for (int fn = 0; fn < 7; ++fn) {
                int n = fn * 16 + l15;
                int ol = (wave - 4) * 64 + fo * 16 + lg * 4;
                f32x4 a = acc[fo][fn];
                bf16x4 w = {(bf16)a[0], (bf16)a[1], (bf16)a[2], (bf16)a[3]};
                *(bf16x4*)(smem + n * SLAB_STRIDE + ol * 2) = w;
            }
    }
    __syncthreads();
    {
        bf16* dst = c3p + (size_t)b * CIN * MPAD + h2 * 28;
        for (int u = t; u < 3584; u += 512) {
            int c = u / 14, w2p = u - c * 14;
            bf16x2 o_;
            #pragma unroll
            for (int k = 0; k < 2; ++k) {
                int w2 = 2 * w2p + k;
                float p0 = (float)*(bf16*)(smem + (2 * w2)      * SLAB_STRIDE + c * 2);
                float p1 = (float)*(bf16*)(smem + (2 * w2 + 1)  * SLAB_STRIDE + c * 2);
                float p2 = (float)*(bf16*)(smem + (56 + 2 * w2) * SLAB_STRIDE + c * 2);
                float p3 = (float)*(bf16*)(smem + (57 + 2 * w2) * SLAB_STRIDE + c * 2);
                float mx = fmaxf(fmaxf(p0, p1), fmaxf(p2, p3));
                float av = (p0 + p1 + p2 + p3) * 0.25f;
                o_[k] = (bf16)(mx + av);
            }
            *(bf16x2*)(dst + (size_t)c * MPAD + 2 * w2p) = o_;
        }
    }
}

// ---------------------------------------------------------------------------
// k_attn v11 = v8 (R11, 183 us) with ONE change: the PV V-stage involution
// uses (row>>1)&3 instead of row&3, turning the staged B-read from a 4-way
// bank conflict into 2-way (free). Write side pre-swizzles the global source
// identically (rule #21); content resolves to slot lg either way.
// ---------------------------------------------------------------------------
#define STG_OFF 114688

__global__ __launch_bounds__(512) void k_attn(
    const bf16* __restrict__ c2n,
    const bf16* __restrict__ c1pT,
    const bf16* __restrict__ c3p,
    const float* __restrict__ x,
    const float* __restrict__ gamma,
    float* __restrict__ out)
{
    const int nb = blockIdx.x, b = blockIdx.y;
    const int n0 = nb * 64;
    const int t = threadIdx.x;
    const int lane = t & 63, wave = t >> 6;
    const int l15 = lane & 15, lg = lane >> 4;
    const int p = wave & 3, h = wave >> 2;

    __shared__ __align__(16) unsigned char smem[147456];
    unsigned char* stg = smem + STG_OFF;
    float* EX = (float*)stg;

    // ---- B-frags: c2 columns for n = n0 + p*16 + l15 (regs, loaded once) ---
    bf16x8 bq[4];
    {
        const bf16* c2b = c2n + ((size_t)b * NPIX + n0 + p * 16 + l15) * CHALF + lg * 8;
        #pragma unroll
        for (int k = 0; k < 4; ++k) bq[k] = *(const bf16x8*)(c2b + k * 32);
    }
    const bf16* c1b = c1pT + (size_t)b * MPAD * CHALF;
    const bf16* c3b = c3p + (size_t)b * CIN * MPAD;

    // ---- S staging addressing: chunk = [64 rows][16 slots x 16B] = 16 KB ---
    const int r0 = t >> 4, s0 = t & 15;
    const int cs = (s0 & 8) | ((s0 & 7) ^ (r0 & 7));
    const bf16* sA = c1b + (size_t)r0 * CHALF + cs * 8;
    const bf16* sB = c1b + (size_t)(448 + r0) * CHALF + cs * 8;

    uint4 rXa, rXb, rYa, rYb;
    rXa = *(const uint4*)(sA);
    rXb = *(const uint4*)(sB);
    *(uint4*)(stg + t * 16) = rXa;
    *(uint4*)(stg + 8192 + t * 16) = rXb;
    rYa = *(const uint4*)(sA + 4096);
    rYb = *(const uint4*)(sB + 4096);
    __syncthreads();

    f32x4 sacc[28];
    #pragma unroll
    for (int j = 0; j < 28; ++j) {
        f32x4 z = {0.f, 0.f, 0.f, 0.f};
        sacc[j] = z;
    }

    #pragma unroll
    for (int mc = 0; mc < 14; ++mc) {
        const unsigned char* bufc = stg + (mc & 1) * 16384;
        unsigned char* bufn = stg + ((mc & 1) ^ 1) * 16384;
        if (mc + 1 < 14) {
            if (mc & 1) { *(uint4*)(bufn + t * 16) = rXa; *(uint4*)(bufn + 8192 + t * 16) = rXb; }
            else        { *(uint4*)(bufn + t * 16) = rYa; *(uint4*)(bufn + 8192 + t * 16) = rYb; }
        }
        if (mc + 2 < 14) {
            if (mc & 1) { rYa = *(const uint4*)(sA + (mc + 2) * 4096); rYb = *(const uint4*)(sB + (mc + 2) * 4096); }
            else        { rXa = *(const uint4*)(sA + (mc + 2) * 4096); rXb = *(const uint4*)(sB + (mc + 2) * 4096); }
        }
        #pragma unroll
        for (int sf = 0; sf < 2; ++sf) {
            bf16x8 af[4];
            #pragma unroll
            for (int k = 0; k < 4; ++k)
                af[k] = *(const bf16x8*)(bufc + h * 8192 + (sf * 16 + l15) * 256
                                         + ((lg * 16 + k * 64) ^ ((l15 & 7) << 4)));
            #pragma unroll
            for (int k = 0; k < 4; ++k)
                sacc[mc * 2 + sf] = __builtin_amdgcn_mfma_f32_16x16x32_bf16(
                    af[k], bq[k], sacc[mc * 2 + sf], 0, 0, 0);
        }
        __syncthreads();
    }

    // ---- in-register softmax; lane n = p*16+l15 holds its 448-m half -------
    float mx = -1e30f;
    #pragma unroll
    for (int j = 0; j < 28; ++j) {
        if (h == 0 || j < 21)
            mx = fmaxf(mx, fmaxf(fmaxf(sacc[j][0], sacc[j][1]),
                                 fmaxf(sacc[j][2], sacc[j][3])));
    }
    mx = fmaxf(mx, __shfl_xor(mx, 16));
    mx = fmaxf(mx, __shfl_xor(mx, 32));
    if (lane < 16) EX[wave * 16 + l15] = mx;
    __syncthreads();
    mx = fmaxf(mx, EX[(wave ^ 4) * 16 + l15]);

    float s = 0.f;
    #pragma unroll
    for (int j = 0; j < 28; ++j) {
        if (h == 0 || j < 21) {
            #pragma unroll
            for (int r = 0; r < 4; ++r) {
                float e = __expf(sacc[j][r] - mx);
                sacc[j][r] = e;
                s += e;
            }
        }
    }
    s += __shfl_xor(s, 16);
    s += __shfl_xor(s, 32);
    if (lane < 16) EX[128 + wave * 16 + l15] = s;
    __syncthreads();
    s += EX[128 + (wave ^ 4) * 16 + l15];
    const float ri = 1.f / s;

    // ---- pre-issue PV chunk 0 (regs) so HBM latency hides under pack -------
    // stage source pre-swizzle: slot ps holds global slot ps^((pc>>1)&3)
    const int pc = t >> 2, ps = t & 3;
    const bf16* sV  = c3b + (size_t)pc * MPAD + ((ps ^ ((pc >> 1) & 3)) * 8);
    const bf16* sV2 = c3b + (size_t)(pc + 128) * MPAD + ((ps ^ ((pc >> 1) & 3)) * 8);
    rXa = *(const uint4*)(sV);
    rXb = *(const uint4*)(sV2);

    // ---- pack normalized P bf16 -> P_lds (single swizzled b64 per frag) ----
    {
        const int n = p * 16 + l15;
        const unsigned sw = (unsigned)((n & 7) << 4);
        const unsigned rowb = (unsigned)(n * 1792);
        #pragma unroll
        for (int j = 0; j < 28; ++j) {
            bf16x4 w;
            if (h == 0 || j < 21) {
                w = bf16x4{ (bf16)(sacc[j][0] * ri), (bf16)(sacc[j][1] * ri),
                            (bf16)(sacc[j][2] * ri), (bf16)(sacc[j][3] * ri) };
            } else {
                w = bf16x4{ (bf16)0.f, (bf16)0.f, (bf16)0.f, (bf16)0.f };
            }
            unsigned byte = rowb + (unsigned)(h * 896 + j * 32 + lg * 8);
            *(bf16x4*)(smem + (byte ^ sw)) = w;
        }
    }
    __syncthreads();    // P complete; EX dead -> stage region free for PV

    // ---- PV phase: v8 pipeline, fixed-granularity involution ---------------
    *(uint4*)(stg + t * 16) = rXa;
    *(uint4*)(stg + 8192 + t * 16) = rXb;
    rYa = *(const uint4*)(sV + 32);
    rYb = *(const uint4*)(sV2 + 32);
    __syncthreads();

    const int wn = h, wq = p;
    f32x4 acc2[2][4];
    #pragma unroll
    for (int fn = 0; fn < 2; ++fn)
        #pragma unroll
        for (int fc = 0; fc < 4; ++fc) {
            f32x4 z = {0.f, 0.f, 0.f, 0.f};
            acc2[fn][fc] = z;
        }

    #pragma unroll
    for (int ks = 0; ks < 28; ++ks) {
        const unsigned char* bufc = stg + (ks & 1) * 16384;
        unsigned char* bufn = stg + ((ks & 1) ^ 1) * 16384;
        if (ks + 1 < 28) {
            if (ks & 1) { *(uint4*)(bufn + t * 16) = rXa; *(uint4*)(bufn + 8192 + t * 16) = rXb; }
            else        { *(uint4*)(bufn + t * 16) = rYa; *(uint4*)(bufn + 8192 + t * 16) = rYb; }
        }
        if (ks + 2 < 28) {
            if (ks & 1) { rYa = *(const uint4*)(sV + (ks + 2) * 32); rYb = *(const uint4*)(sV2 + (ks + 2) * 32); }
            else        { rXa = *(const uint4*)(sV + (ks + 2) * 32); rXb = *(const uint4*)(sV2 + (ks + 2) * 32); }
        }
        {
            int nA0 = wn * 32 + l15, nA1 = nA0 + 16;
            int mb = (ks * 32 + lg * 8) * 2;
            bf16x8 af0 = *(const bf16x8*)(smem + ((nA0 * 1792 + mb) ^ ((nA0 & 7) << 4)));
            bf16x8 af1 = *(const bf16x8*)(smem + ((nA1 * 1792 + mb) ^ ((nA1 & 7) << 4)));
            #pragma unroll
            for (int fc = 0; fc < 4; ++fc) {
                int c = wq * 64 + fc * 16 + l15;
                bf16x8 bfr = *(const bf16x8*)(bufc + c * 64 + ((lg ^ ((c >> 1) & 3)) * 16));
                acc2[0][fc] = __builtin_amdgcn_mfma_f32_16x16x32_bf16(af0, bfr, acc2[0][fc], 0, 0, 0);
                acc2[1][fc] = __builtin_amdgcn_mfma_f32_16x16x32_bf16(af1, bfr, acc2[1][fc], 0, 0, 0);
            }
        }
        __syncthreads();
    }

    // ---- epilogue: transpose via LDS, out = g*refined + x ------------------
    float* R = (float*)smem;    // [64][257], P_lds dead
    #pragma unroll
    for (int fn = 0; fn < 2; ++fn)
        #pragma unroll
        for (int fc = 0; fc < 4; ++fc) {
            int c = wq * 64 + fc * 16 + l15;
            #pragma unroll
            for (int r = 0; r < 4; ++r) {
                int n = wn * 32 + fn * 16 + lg * 4 + r;
                R[n * 257 + c] = acc2[fn][fc][r];
            }
        }
    __syncthreads();
    const float g = gamma[0];
    const float* xb = x + (size_t)b * CIN * NPIX + n0;
    float* ob = out + (size_t)b * CIN * NPIX + n0;
    #pragma unroll 4
    for (int i = 0; i < 32; ++i) {
        int idx = t + i * 512;                  // 256 c x 64 n
        int c = idx >> 6, nn = idx & 63;
        size_t off = (size_t)c * NPIX + nn;
        ob[off] = g * R[nn * 257 + c] + xb[off];
    }
}

extern "C" void kernel_launch(void* const* d_in, const int* in_sizes, int n_in,
                              void* d_out, int out_size, void* d_ws, size_t ws_size,
                              hipStream_t stream) {
    const float* x     = (const float*)d_in[0];
    const float* W1    = (const float*)d_in[1];
    const float* W2    = (const float*)d_in[2];
    const float* W3    = (const float*)d_in[3];
    const float* gamma = (const float*)d_in[4];
    float* out = (float*)d_out;

    bf16* ws   = (bf16*)d_ws;
    bf16* Wcat = ws;                                       // 512*256
    bf16* c2n  = Wcat + (size_t)512 * 256;                 // 32*3136*128
    bf16* c1pT = c2n + (size_t)BATCH * NPIX * CHALF;       // 32*896*128
    bf16* c3p  = c1pT + (size_t)BATCH * MPAD * CHALF;      // 32*256*896

    k_cast<<<128, 256, 0, stream>>>(W1, W2, W3, Wcat);
    k_conv<<<dim3(28, BATCH), 512, 0, stream>>>(x, Wcat, c2n, c1pT, c3p);
    k_attn<<<dim3(49, BATCH), 512, 0, stream>>>(c2n, c1pT, c3p, x, gamma, out);
}